// Round 10
// baseline (718.160 us; speedup 1.0000x reference)
//
#include <hip/hip_runtime.h>
#include <math.h>

#define BATCH 512
#define ITERS 1000

typedef float f32x2 __attribute__((ext_vector_type(2)));
typedef float f32x4 __attribute__((ext_vector_type(4)));

// readlane requires a WAVE-UNIFORM lane index (all uses are constants here).
__device__ __forceinline__ float rdlane(float v, int l) {
  return __int_as_float(__builtin_amdgcn_readlane(__float_as_int(v), l));
}
__device__ __forceinline__ f32x2 fma2(f32x2 a, f32x2 b, f32x2 c) {
#if __has_builtin(__builtin_elementwise_fma)
  return __builtin_elementwise_fma(a, b, c);
#else
  f32x2 r; r.x = fmaf(a.x, b.x, c.x); r.y = fmaf(a.y, b.y, c.y); return r;
#endif
}

// Register-resident Gauss-Jordan on [A|I] (32x64); lane holds column `lane`.
#define GJ32_REG(g)                                            \
  _Pragma("unroll")                                            \
  for (int k = 0; k < 32; ++k) {                               \
    float inv = 1.0f / rdlane(g[k], k);                        \
    g[k] *= inv;                                               \
    _Pragma("unroll")                                          \
    for (int ii = 0; ii < 32; ++ii) {                          \
      if (ii == k) continue;                                   \
      float f = rdlane(g[ii], k);                              \
      g[ii] = fmaf(-f, g[k], g[ii]);                           \
    }                                                          \
  }

// ---- 1 block x 64 threads: Hinv = (H^T H)^-1 H^T -> ws[r*64+lane] ----
// Single-wave LDS staging: per-wave DS is program-ordered; aliasing through
// the same __shared__ array prevents compiler reordering (proven in r8).
__global__ __launch_bounds__(64) void hinv_kernel(const float* __restrict__ H,
                                                  float* __restrict__ ws) {
  __shared__ float hstage[64 * 34];
  const int lane = threadIdx.x;
  const int l = lane & 31;
  float hreg[32];
  {
    const f32x4* hp = (const f32x4*)(H + lane * 32);
    #pragma unroll
    for (int j4 = 0; j4 < 8; ++j4) {
      f32x4 t = hp[j4];
      hreg[4*j4+0] = t.x; hreg[4*j4+1] = t.y; hreg[4*j4+2] = t.z; hreg[4*j4+3] = t.w;
    }
  }
  #pragma unroll
  for (int j = 0; j < 32; ++j) hstage[lane * 34 + j] = hreg[j];
  float htc[64];                          // htc[m] = H[m][l]
  #pragma unroll
  for (int m = 0; m < 64; ++m) htc[m] = hstage[m * 34 + l];
  float gB[32];
  #pragma unroll
  for (int r = 0; r < 32; ++r) {
    float a0 = 0.f, a1 = 0.f;
    #pragma unroll
    for (int m = 0; m < 64; m += 2) {
      a0 = fmaf(rdlane(hreg[r], m),     htc[m],     a0);
      a1 = fmaf(rdlane(hreg[r], m + 1), htc[m + 1], a1);
    }
    float hth = a0 + a1;                  // (H^T H)[r][l]
    gB[r] = (lane < 32) ? hth : (((lane - 32) == r) ? 1.0f : 0.0f);
  }
  GJ32_REG(gB)
  #pragma unroll
  for (int r = 0; r < 32; ++r) {          // Hinv[r][lane]
    float a0 = 0.f, a1 = 0.f;
    #pragma unroll
    for (int c = 0; c < 32; c += 2) {
      a0 = fmaf(rdlane(gB[r], 32 + c),     hreg[c],     a0);
      a1 = fmaf(rdlane(gB[r], 32 + c + 1), hreg[c + 1], a1);
    }
    ws[r * 64 + lane] = a0 + a1;
  }
}

// ---- 512 blocks x 64 threads: setup (registers) + 1000-iter recurrence ----
// One wave per batch row; lane i holds row i of s*D; x1 broadcast via
// v_readlane. This is the r2 iterator (measured 578 cyc/iter standalone)
// with the per-block register setup from r9 folded in (~23 us, parallel).
__global__ __launch_bounds__(64) void iter_kernel(const float* __restrict__ q,
                                                  const float* __restrict__ bmat,
                                                  const float* __restrict__ P,
                                                  const float* __restrict__ H,
                                                  float* __restrict__ Xs) {
  const int row = blockIdx.x, lane = threadIdx.x;
  const int i = lane & 31;

  float hreg[32];
  {
    const f32x4* hp = (const f32x4*)(H + lane * 32);
    #pragma unroll
    for (int j4 = 0; j4 < 8; ++j4) {
      f32x4 t = hp[j4];
      hreg[4*j4+0] = t.x; hreg[4*j4+1] = t.y; hreg[4*j4+2] = t.z; hreg[4*j4+3] = t.w;
    }
  }
  const float bl = bmat[(size_t)row * 64 + lane];

  // ---------- setup: P^-1, P^-1 H^T, D, lambda_max via power iter on D^2 ----
  float dcol[64], s, mu;
  {
    float pht[32], acc;
    {
      float g[32];
      #pragma unroll
      for (int r = 0; r < 32; ++r) {
        float pv = P[r * 32 + i];
        g[r] = (lane < 32) ? pv : (((lane - 32) == r) ? 1.0f : 0.0f);
      }
      GJ32_REG(g)
      #pragma unroll
      for (int r = 0; r < 32; ++r) {      // (P^-1 H^T)[r][lane]
        float a0 = 0.f, a1 = 0.f;
        #pragma unroll
        for (int j = 0; j < 32; j += 2) {
          a0 = fmaf(rdlane(g[r], 32 + j),     hreg[j],     a0);
          a1 = fmaf(rdlane(g[r], 32 + j + 1), hreg[j + 1], a1);
        }
        pht[r] = a0 + a1;
      }
    }
    {
      const float* qp = q + (size_t)row * 32;      // wave-uniform -> s_loads
      float a0 = 0.f, a1 = 0.f;
      #pragma unroll
      for (int r = 0; r < 32; r += 2) {
        a0 = fmaf(qp[r],     pht[r],     a0);
        a1 = fmaf(qp[r + 1], pht[r + 1], a1);
      }
      acc = a0 + a1;                      // (H P^-1 q)[lane]
    }
    #pragma unroll
    for (int r = 0; r < 64; ++r) {        // D[r][lane] (symmetric)
      float a0 = 0.f, a1 = 0.f;
      #pragma unroll
      for (int j = 0; j < 32; j += 2) {
        a0 = fmaf(rdlane(hreg[j],     r), pht[j],     a0);
        a1 = fmaf(rdlane(hreg[j + 1], r), pht[j + 1], a1);
      }
      dcol[r] = a0 + a1;
    }
    {
      float ecol[64];                     // E = D^2 (squares convergence rate)
      #pragma unroll
      for (int r = 0; r < 64; ++r) {
        float a0 = 0.f, a1 = 0.f;
        #pragma unroll
        for (int c = 0; c < 64; c += 2) {
          a0 = fmaf(rdlane(dcol[r], c),     dcol[c],     a0);
          a1 = fmaf(rdlane(dcol[r], c + 1), dcol[c + 1], a1);
        }
        ecol[r] = a0 + a1;
      }
      float v = 1.0f + 0.017f * (float)lane;
      #pragma unroll 1
      for (int t = 0; t < 112; ++t) {
        float a0 = 0.f, a1 = 0.f, a2 = 0.f, a3 = 0.f;
        #pragma unroll
        for (int c = 0; c < 64; c += 4) {
          a0 = fmaf(ecol[c+0], rdlane(v, c+0), a0);
          a1 = fmaf(ecol[c+1], rdlane(v, c+1), a1);
          a2 = fmaf(ecol[c+2], rdlane(v, c+2), a2);
          a3 = fmaf(ecol[c+3], rdlane(v, c+3), a3);
        }
        v = (a0 + a1) + (a2 + a3);
        if ((t & 7) == 7) {
          float n2 = v * v;
          #pragma unroll
          for (int m = 1; m < 64; m <<= 1) n2 += __shfl_xor(n2, m);
          v *= 1.0f / sqrtf(n2);
        }
      }
      float a0 = 0.f, a1 = 0.f, a2 = 0.f, a3 = 0.f;  // Rayleigh with D
      #pragma unroll
      for (int c = 0; c < 64; c += 4) {
        a0 = fmaf(dcol[c+0], rdlane(v, c+0), a0);
        a1 = fmaf(dcol[c+1], rdlane(v, c+1), a1);
        a2 = fmaf(dcol[c+2], rdlane(v, c+2), a2);
        a3 = fmaf(dcol[c+3], rdlane(v, c+3), a3);
      }
      float w = (a0 + a1) + (a2 + a3);
      float num = w * v, den = v * v;
      #pragma unroll
      for (int m = 1; m < 64; m <<= 1) {
        num += __shfl_xor(num, m);
        den += __shfl_xor(den, m);
      }
      s = den / num;                      // s = 1 / lambda_max(D)
    }
    mu = s * (acc - bl);
    #pragma unroll
    for (int r = 0; r < 64; ++r) dcol[r] *= s;   // row `lane` of s*D
  }

  // ---------- main loop (r2-proven): 1000 iterations ----------
  float x1 = 0.f, x2 = 0.f;
  float* Xp = Xs + (size_t)row * (ITERS + 1) * 128;
  Xp[lane] = 0.f;                         // X0 = 0
  Xp[64 + lane] = 0.f;

  #pragma unroll 1
  for (int k = 1; k <= ITERS; ++k) {
    float a0 = 0.f, a1 = 0.f, a2 = 0.f, a3 = 0.f;
    #pragma unroll
    for (int j = 0; j < 64; j += 4) {
      a0 = fmaf(dcol[j+0], rdlane(x1, j+0), a0);
      a1 = fmaf(dcol[j+1], rdlane(x1, j+1), a1);
      a2 = fmaf(dcol[j+2], rdlane(x1, j+2), a2);
      a3 = fmaf(dcol[j+3], rdlane(x1, j+3), a3);
    }
    float x1n = ((a0 + a1) + (a2 + a3)) + fmaf(s, x2, mu);
    float x2n = fmaxf(fmaf(-2.0f, x1n, x1 + x2), 0.f);
    Xp += 128;
    Xp[lane] = x1n;
    Xp[64 + lane] = x2n;
    x1 = x1n; x2 = x2n;
  }
}

// ---- 512 blocks x 512 threads: primal_sols (r2-proven, Hinv from ws) ----
__global__ __launch_bounds__(512) void primal_kernel(const float* __restrict__ bmat,
                                                     const float* __restrict__ ws,
                                                     const float* __restrict__ Xs,
                                                     float* __restrict__ out2) {
  const int row = blockIdx.x;
  const int tid = threadIdx.x;
  const int wv = tid >> 6, lane = tid & 63;
  const int i = lane & 31, h = lane >> 5;
  __shared__ __align__(16) float tbuf[8][64];

  float hv[32];   // half-row of Hinv: h=0 -> j 0..31, h=1 -> j 32..63
  {
    const f32x4* hp = (const f32x4*)(ws + i * 64 + h * 32);
    #pragma unroll
    for (int j4 = 0; j4 < 8; ++j4) {
      f32x4 t = hp[j4];
      hv[4*j4+0] = t.x; hv[4*j4+1] = t.y; hv[4*j4+2] = t.z; hv[4*j4+3] = t.w;
    }
  }
  const float bl = bmat[(size_t)row * 64 + lane];
  const float* Xb = Xs + (size_t)row * (ITERS + 1) * 128 + 64;
  float* ob = out2 + (size_t)row * (ITERS + 1) * 32;

  float tA = Xb[(size_t)wv * 128 + lane] - bl;                          // k = wv
  float tB = (wv + 8 <= ITERS) ? Xb[(size_t)(wv + 8) * 128 + lane] - bl : 0.f;

  #pragma unroll 1
  for (int k = wv; k <= ITERS; k += 8) {
    const int kn = k + 16;
    float tC = (kn <= ITERS) ? Xb[(size_t)kn * 128 + lane] - bl : 0.f;  // prefetch
    tbuf[wv][lane] = tA;
    __builtin_amdgcn_wave_barrier();          // fence; wave-private slot, in-order DS
    float a0 = 0.f, a1 = 0.f, a2 = 0.f, a3 = 0.f;
    const f32x4* tp = (const f32x4*)&tbuf[wv][h * 32];
    #pragma unroll
    for (int j4 = 0; j4 < 8; ++j4) {
      f32x4 t = tp[j4];
      a0 = fmaf(hv[4*j4+0], t.x, a0);
      a1 = fmaf(hv[4*j4+1], t.y, a1);
      a2 = fmaf(hv[4*j4+2], t.z, a2);
      a3 = fmaf(hv[4*j4+3], t.w, a3);
    }
    float p = (a0 + a1) + (a2 + a3);
    p += __shfl_xor(p, 32);                   // combine j-halves
    if (h == 0) ob[(size_t)k * 32 + i] = p;
    __builtin_amdgcn_wave_barrier();          // next write stays after these reads
    tA = tB; tB = tC;
  }
}

extern "C" void kernel_launch(void* const* d_in, const int* in_sizes, int n_in,
                              void* d_out, int out_size, void* d_ws, size_t ws_size,
                              hipStream_t stream) {
  (void)in_sizes; (void)n_in; (void)out_size; (void)ws_size;
  const float* q = (const float*)d_in[0];
  const float* b = (const float*)d_in[1];
  const float* P = (const float*)d_in[2];
  const float* H = (const float*)d_in[3];
  float* ws = (float*)d_ws;               // 32x64 Hinv
  float* Xs = (float*)d_out;
  float* out2 = Xs + (size_t)BATCH * (ITERS + 1) * 128;

  hinv_kernel<<<1, 64, 0, stream>>>(H, ws);
  iter_kernel<<<BATCH, 64, 0, stream>>>(q, b, P, H, Xs);
  primal_kernel<<<BATCH, 512, 0, stream>>>(b, ws, Xs, out2);
}